// Round 4
// baseline (3049.713 us; speedup 1.0000x reference)
//
#include <hip/hip_runtime.h>
#include <hip/hip_bf16.h>
#include <math.h>

#define B_ 64
#define T_ 60
#define S_ 60
#define H_ 512
#define V_ 32000
#define L_ 2
#define BT_ (B_*T_)
#define LDSROW 40
#define NBLK 32
#define FLAGSTRIDE 32   // ints between flags (128B, separate cache lines)

typedef __attribute__((ext_vector_type(8))) short short8;
typedef __attribute__((ext_vector_type(4))) float f32x4;

__device__ __forceinline__ short f2bf(float x) {
  __hip_bfloat16 h = __float2bfloat16(x);
  return __builtin_bit_cast(short, h);
}
__device__ __forceinline__ float bf2f(short s) {
  unsigned int u = ((unsigned int)(unsigned short)s) << 16;
  return __builtin_bit_cast(float, u);
}
__device__ __forceinline__ float sigm(float x) { return 1.f / (1.f + __expf(-x)); }
__device__ __forceinline__ float tanh_(float x) {
  float e = __expf(-2.f * fabsf(x));
  float t = (1.f - e) / (1.f + e);
  return x >= 0.f ? t : -t;
}

// ---------------- f32 -> bf16 bulk convert ----------------
__global__ __launch_bounds__(256) void convbf_k(const float* __restrict__ src,
                                                short* __restrict__ dst) {
  int g = blockIdx.x * 256 + threadIdx.x;
  const float* s = src + (size_t)g * 8;
  float4 v0 = *(const float4*)s, v1 = *(const float4*)(s + 4);
  short8 o;
  o[0]=f2bf(v0.x); o[1]=f2bf(v0.y); o[2]=f2bf(v0.z); o[3]=f2bf(v0.w);
  o[4]=f2bf(v1.x); o[5]=f2bf(v1.y); o[6]=f2bf(v1.z); o[7]=f2bf(v1.w);
  *(short8*)(dst + (size_t)g * 8) = o;
}

// ---- pack whh[2,2048,512] f32 -> block-permuted fragment-ordered bf16 ----
// original n = g*512 + j; permuted row np = (j>>4)*64 + g*16 + (j&15)
// frag offset(np,k) = ((np>>4)*64 + (k>>3))*128 + (np&15)*8 + (k&7)
__global__ __launch_bounds__(256) void pack_whh_k(const float* __restrict__ whh,
                                                  short* __restrict__ pk) {
  int idx = blockIdx.x * 256 + threadIdx.x;
  int l = idx >> 17, rem = idx & 131071;
  int n = rem >> 6, k8 = rem & 63;
  int g = n >> 9, j = n & 511;
  int np = (j >> 4) * 64 + g * 16 + (j & 15);
  const float* src = whh + ((size_t)l * 2048 + n) * 512 + k8 * 8;
  float4 v0 = *(const float4*)src, v1 = *(const float4*)(src + 4);
  short8 o;
  o[0]=f2bf(v0.x); o[1]=f2bf(v0.y); o[2]=f2bf(v0.z); o[3]=f2bf(v0.w);
  o[4]=f2bf(v1.x); o[5]=f2bf(v1.y); o[6]=f2bf(v1.z); o[7]=f2bf(v1.w);
  size_t dst = (size_t)l * (2048 * 512) + ((size_t)((np >> 4) * 64 + k8)) * 128 + (np & 15) * 8;
  *(short8*)(pk + dst) = o;
}

// ---------------- embedding gather ----------------
__global__ __launch_bounds__(256) void embed_k(const int* __restrict__ idx,
                                               const float* __restrict__ emb,
                                               float* __restrict__ x) {
  int e = blockIdx.x * 256 + threadIdx.x;
  int bt = e >> 9, h = e & (H_ - 1);
  int row = idx[bt];
  x[e] = emb[(size_t)row * H_ + h];
}

// ------- C = A(f32, split hi/lo) @ Bw(f32->bf16)^T + bias1[+bias2] ----------
template<bool XPOSE>
__global__ __launch_bounds__(256) void gemm_a32_k(
    const float* __restrict__ A, const float* __restrict__ Bw,
    const float* __restrict__ bias1, const float* __restrict__ bias2,
    float* __restrict__ C, short* __restrict__ Cbf, int M, int N, int K) {
  __shared__ short Ahs[128 * LDSROW];
  __shared__ short Als[128 * LDSROW];
  __shared__ short Bs[128 * LDSROW];
  int tid = threadIdx.x;
  int bm = blockIdx.y * 128, bn = blockIdx.x * 128;
  int wid = tid >> 6, lane = tid & 63;
  int wr = wid >> 1, wc = wid & 1;
  int lrow = lane & 15, lk = (lane >> 4) * 8;
  f32x4 acc[4][4];
#pragma unroll
  for (int i = 0; i < 4; ++i)
#pragma unroll
    for (int j = 0; j < 4; ++j) acc[i][j] = (f32x4){0.f, 0.f, 0.f, 0.f};

  int srow = tid >> 2, scol = (tid & 3) * 8;

  for (int k0 = 0; k0 < K; k0 += 32) {
#pragma unroll
    for (int it = 0; it < 2; ++it) {
      int r = srow + it * 64;
      const float* ap = A + (size_t)(bm + r) * K + k0 + scol;
      float4 a0 = *(const float4*)ap, a1 = *(const float4*)(ap + 4);
      float av[8] = {a0.x,a0.y,a0.z,a0.w,a1.x,a1.y,a1.z,a1.w};
      short8 hv, lv;
#pragma unroll
      for (int e = 0; e < 8; ++e) {
        short h = f2bf(av[e]);
        hv[e] = h;
        lv[e] = f2bf(av[e] - bf2f(h));
      }
      *(short8*)(Ahs + r * LDSROW + scol) = hv;
      *(short8*)(Als + r * LDSROW + scol) = lv;
      const float* bp = Bw + (size_t)(bn + r) * K + k0 + scol;
      float4 b0 = *(const float4*)bp, b1 = *(const float4*)(bp + 4);
      short8 bv;
      bv[0]=f2bf(b0.x); bv[1]=f2bf(b0.y); bv[2]=f2bf(b0.z); bv[3]=f2bf(b0.w);
      bv[4]=f2bf(b1.x); bv[5]=f2bf(b1.y); bv[6]=f2bf(b1.z); bv[7]=f2bf(b1.w);
      *(short8*)(Bs + r * LDSROW + scol) = bv;
    }
    __syncthreads();
    short8 ah[4], al[4], bfr[4];
#pragma unroll
    for (int i = 0; i < 4; ++i) {
      ah[i] = *(const short8*)(Ahs + (wr * 64 + i * 16 + lrow) * LDSROW + lk);
      al[i] = *(const short8*)(Als + (wr * 64 + i * 16 + lrow) * LDSROW + lk);
    }
#pragma unroll
    for (int j = 0; j < 4; ++j)
      bfr[j] = *(const short8*)(Bs + (wc * 64 + j * 16 + lrow) * LDSROW + lk);
#pragma unroll
    for (int i = 0; i < 4; ++i)
#pragma unroll
      for (int j = 0; j < 4; ++j) {
        acc[i][j] = __builtin_amdgcn_mfma_f32_16x16x32_bf16(ah[i], bfr[j], acc[i][j], 0, 0, 0);
        acc[i][j] = __builtin_amdgcn_mfma_f32_16x16x32_bf16(al[i], bfr[j], acc[i][j], 0, 0, 0);
      }
    __syncthreads();
  }

#pragma unroll
  for (int j = 0; j < 4; ++j) {
    int col = bn + wc * 64 + j * 16 + lrow;
    float bv = bias1[col] + (bias2 ? bias2[col] : 0.f);
#pragma unroll
    for (int i = 0; i < 4; ++i) {
#pragma unroll
      for (int r = 0; r < 4; ++r) {
        int row = bm + wr * 64 + i * 16 + (lane >> 4) * 4 + r;
        float v = acc[i][j][r] + bv;
        if (XPOSE) {
          int b = row / T_, t = row - b * T_;
          C[((size_t)t * B_ + b) * N + col] = v;
        } else {
          C[(size_t)row * N + col] = v;
          if (Cbf) Cbf[(size_t)row * N + col] = f2bf(v);
        }
      }
    }
  }
}

// ---------------- final: C = A(bf16) @ Bbf(bf16)^T + bias ---------------
__global__ __launch_bounds__(256) void gemm_bb_k(
    const short* __restrict__ A, const short* __restrict__ Bbf,
    const float* __restrict__ bias, float* __restrict__ C) {
  const int N = V_, K = H_;
  int n = blockIdx.x;
  int xcd = n & 7, pos = n >> 3;
  int base = (xcd < 4) ? xcd * 938 : 4 * 938 + (xcd - 4) * 937;
  int wg = base + pos;
  int bm = (wg % 30) * 128;
  int bn = (wg / 30) * 128;

  __shared__ short As[128 * LDSROW];
  __shared__ short Bs[128 * LDSROW];
  int tid = threadIdx.x;
  int wid = tid >> 6, lane = tid & 63;
  int wr = wid >> 1, wc = wid & 1;
  int lrow = lane & 15, lk = (lane >> 4) * 8;
  f32x4 acc[4][4];
#pragma unroll
  for (int i = 0; i < 4; ++i)
#pragma unroll
    for (int j = 0; j < 4; ++j) acc[i][j] = (f32x4){0.f, 0.f, 0.f, 0.f};

  int srow = tid >> 2, scol = (tid & 3) * 8;

  for (int k0 = 0; k0 < K; k0 += 32) {
#pragma unroll
    for (int it = 0; it < 2; ++it) {
      int r = srow + it * 64;
      short8 av = *(const short8*)(A + (size_t)(bm + r) * K + k0 + scol);
      *(short8*)(As + r * LDSROW + scol) = av;
      short8 bv = *(const short8*)(Bbf + (size_t)(bn + r) * K + k0 + scol);
      *(short8*)(Bs + r * LDSROW + scol) = bv;
    }
    __syncthreads();
    short8 af[4], bfr[4];
#pragma unroll
    for (int i = 0; i < 4; ++i)
      af[i] = *(const short8*)(As + (wr * 64 + i * 16 + lrow) * LDSROW + lk);
#pragma unroll
    for (int j = 0; j < 4; ++j)
      bfr[j] = *(const short8*)(Bs + (wc * 64 + j * 16 + lrow) * LDSROW + lk);
#pragma unroll
    for (int i = 0; i < 4; ++i)
#pragma unroll
      for (int j = 0; j < 4; ++j)
        acc[i][j] = __builtin_amdgcn_mfma_f32_16x16x32_bf16(af[i], bfr[j], acc[i][j], 0, 0, 0);
    __syncthreads();
  }

#pragma unroll
  for (int j = 0; j < 4; ++j) {
    int col = bn + wc * 64 + j * 16 + lrow;
    float bv = bias[col];
#pragma unroll
    for (int i = 0; i < 4; ++i)
#pragma unroll
      for (int r = 0; r < 4; ++r) {
        int row = bm + wr * 64 + i * 16 + (lane >> 4) * 4 + r;
        C[(size_t)row * N + col] = acc[i][j][r] + bv;
      }
  }
}

// ------------- persistent LSTM, 32 blocks, distributed flag sync ------------
// Block jb owns j in [jb*16, jb*16+16), all 4 gates. Wave w: mtile=w>>1
// (16 batches), kh=w&1 (K half). whh fragment resident in VGPRs.
// h: hi/lo bf16 planes, double buffered. flags[jb*FLAGSTRIDE] = steps done.
__global__ __launch_bounds__(512, 2) void lstm_seq_k(
    const float* __restrict__ xg,      // [T,B,4H], both biases pre-added
    const short* __restrict__ whh_pk,  // packed bf16
    short* __restrict__ hb,            // 2 bufs x hi/lo x (64*512)
    float* __restrict__ dec,           // [B,T,H]
    int* __restrict__ flags) {
  __shared__ float gall[2][64 * 65];
  int tid = threadIdx.x;
  int jb = blockIdx.x;
  int w = tid >> 6, lane = tid & 63;
  int lr = lane & 15, lkg = lane >> 4;
  int mtile = w >> 1, kh = w & 1;

  short8 wreg[4][8];
#pragma unroll
  for (int nt = 0; nt < 4; ++nt)
#pragma unroll
    for (int k8 = 0; k8 < 8; ++k8) {
      int rowtile = jb * 4 + nt;
      int kt = kh * 8 + k8;
      wreg[nt][k8] = *(const short8*)(whh_pk +
          ((size_t)(rowtile * 64 + kt * 4 + lkg)) * 128 + lr * 8);
    }

  float cc0 = 0.f, cc1 = 0.f;
  const int b0a = tid >> 4;
  const int jja = tid & 15;
  const int jglob = jb * 16 + jja;
  const int aoff = (mtile * 16 + lr) * 512 + kh * 256 + lkg * 8;

  for (int t = 0; t < T_; ++t) {
    // prefetch xg for this step (independent of h; hides under the poll)
    float xgv[2][4];
#pragma unroll
    for (int half = 0; half < 2; ++half) {
      int b = b0a + half * 32;
#pragma unroll
      for (int g = 0; g < 4; ++g)
        xgv[half][g] = xg[((size_t)t * B_ + b) * 2048 + g * 512 + jglob];
    }

    // wait for the 16 producers of our K half (h(t) slices)
    if (t > 0) {
      if (lane < 16) {
        const int* fp = flags + (kh * 16 + lane) * FLAGSTRIDE;
        while (__hip_atomic_load(fp, __ATOMIC_ACQUIRE, __HIP_MEMORY_SCOPE_AGENT) < t)
          __builtin_amdgcn_s_sleep(1);
      }
      __threadfence();
    }

    const short* rh = hb + (size_t)(t & 1) * 65536;
    const short* rl = rh + 32768;
    f32x4 acc[4];
#pragma unroll
    for (int nt = 0; nt < 4; ++nt) acc[nt] = (f32x4){0.f, 0.f, 0.f, 0.f};
#pragma unroll
    for (int k8 = 0; k8 < 8; ++k8) {
      short8 ah = *(const short8*)(rh + aoff + k8 * 32);
      short8 al = *(const short8*)(rl + aoff + k8 * 32);
#pragma unroll
      for (int nt = 0; nt < 4; ++nt) {
        acc[nt] = __builtin_amdgcn_mfma_f32_16x16x32_bf16(ah, wreg[nt][k8], acc[nt], 0, 0, 0);
        acc[nt] = __builtin_amdgcn_mfma_f32_16x16x32_bf16(al, wreg[nt][k8], acc[nt], 0, 0, 0);
      }
    }
#pragma unroll
    for (int nt = 0; nt < 4; ++nt)
#pragma unroll
      for (int r = 0; r < 4; ++r)
        gall[kh][(nt * 16 + lr) * 65 + mtile * 16 + lkg * 4 + r] = acc[nt][r];
    __syncthreads();

    short* wh = hb + (size_t)((t & 1) ^ 1) * 65536;
#pragma unroll
    for (int half = 0; half < 2; ++half) {
      int b = b0a + half * 32;
      float gv[4];
#pragma unroll
      for (int g = 0; g < 4; ++g)
        gv[g] = gall[0][(g * 16 + jja) * 65 + b] + gall[1][(g * 16 + jja) * 65 + b]
              + xgv[half][g];
      float cold = half ? cc1 : cc0;
      float cn = sigm(gv[1]) * cold + sigm(gv[0]) * tanh_(gv[2]);
      float hn = sigm(gv[3]) * tanh_(cn);
      if (half) cc1 = cn; else cc0 = cn;
      short hi_ = f2bf(hn);
      wh[b * 512 + jglob] = hi_;
      wh[32768 + b * 512 + jglob] = f2bf(hn - bf2f(hi_));
      dec[((size_t)b * T_ + t) * H_ + jglob] = hn;
    }
    __threadfence();
    __syncthreads();
    if (tid == 0)
      __hip_atomic_store(flags + jb * FLAGSTRIDE, t + 1,
                         __ATOMIC_RELEASE, __HIP_MEMORY_SCOPE_AGENT);
  }
}

// ---------------- attention + softmax + concat (f32) ----------------
__global__ __launch_bounds__(256) void attn_k(const float* __restrict__ dec,
                                              const float* __restrict__ enc,
                                              const int* __restrict__ lens,
                                              float* __restrict__ cat) {
  int bt = blockIdx.x;
  int b = bt / T_;
  __shared__ float dsh[H_];
  __shared__ float p[64];
  int tid = threadIdx.x;
  dsh[tid] = dec[(size_t)bt * H_ + tid];
  dsh[tid + 256] = dec[(size_t)bt * H_ + tid + 256];
  __syncthreads();
  int wid = tid >> 6, lane = tid & 63;
  int len = lens[b];
  for (int s = wid; s < S_; s += 4) {
    const float* er = enc + ((size_t)(b * S_ + s)) * H_ + lane * 8;
    float4 e0 = *(const float4*)er, e1 = *(const float4*)(er + 4);
    const float* dr = dsh + lane * 8;
    float sum = e0.x*dr[0] + e0.y*dr[1] + e0.z*dr[2] + e0.w*dr[3]
              + e1.x*dr[4] + e1.y*dr[5] + e1.z*dr[6] + e1.w*dr[7];
#pragma unroll
    for (int off = 32; off > 0; off >>= 1) sum += __shfl_down(sum, off);
    if (lane == 0) p[s] = sum + (s < len ? 0.f : -1.0e9f);
  }
  __syncthreads();
  if (wid == 0) {
    float v = (lane < S_) ? p[lane] : -INFINITY;
    float m = v;
#pragma unroll
    for (int off = 32; off > 0; off >>= 1) m = fmaxf(m, __shfl_down(m, off));
    m = __shfl(m, 0);
    float e = (lane < S_) ? expf(v - m) : 0.f;
    float ssum = e;
#pragma unroll
    for (int off = 32; off > 0; off >>= 1) ssum += __shfl_down(ssum, off);
    ssum = __shfl(ssum, 0);
    if (lane < S_) p[lane] = e / ssum;
  }
  __syncthreads();
  int h = tid * 2;
  float a0 = 0.f, a1 = 0.f;
  for (int s = 0; s < S_; ++s) {
    float ps = p[s];
    const float* er = enc + ((size_t)(b * S_ + s)) * H_ + h;
    a0 += ps * er[0];
    a1 += ps * er[1];
  }
  size_t base = (size_t)bt * (2 * H_);
  cat[base + h]          = dsh[h];
  cat[base + h + 1]      = dsh[h + 1];
  cat[base + H_ + h]     = a0;
  cat[base + H_ + h + 1] = a1;
}

extern "C" void kernel_launch(void* const* d_in, const int* in_sizes, int n_in,
                              void* d_out, int out_size, void* d_ws, size_t ws_size,
                              hipStream_t stream) {
  (void)in_sizes; (void)n_in; (void)out_size; (void)ws_size;
  const int*   indices = (const int*)d_in[0];
  const float* enc     = (const float*)d_in[1];
  const int*   de_lens = (const int*)d_in[2];
  const float* emb     = (const float*)d_in[3];
  const float* w_ih    = (const float*)d_in[4];
  const float* w_hh    = (const float*)d_in[5];
  const float* b_ih    = (const float*)d_in[6];
  const float* b_hh    = (const float*)d_in[7];
  const float* lin_w   = (const float*)d_in[8];
  const float* lin_b   = (const float*)d_in[9];
  const float* out_w   = (const float*)d_in[10];
  const float* out_b   = (const float*)d_in[11];
  float* outp = (float*)d_out;

  char* ws = (char*)d_ws;
  size_t off = 0;
  auto alloc = [&](size_t bytes) -> void* {
    void* p = ws + off; off += (bytes + 255) & ~(size_t)255; return p;
  };
  float* x      = (float*)alloc((size_t)BT_ * H_ * 4);
  float* xg     = (float*)alloc((size_t)BT_ * 4 * H_ * 4);      // [T,B,4H]
  float* dec    = (float*)alloc((size_t)BT_ * H_ * 4);          // [B,T,H]
  float* cat    = (float*)alloc((size_t)BT_ * 2 * H_ * 4);
  short* ow_bf  = (short*)alloc((size_t)V_ * H_ * 2);
  short* whh_pk = (short*)alloc((size_t)L_ * 4 * H_ * H_ * 2);
  short* x_bf   = (short*)alloc((size_t)BT_ * H_ * 2);
  short* hb     = (short*)alloc((size_t)4 * B_ * H_ * 2);       // 2 bufs x hi/lo
  int*   flags  = (int*)alloc((size_t)L_ * NBLK * FLAGSTRIDE * 4);

  hipMemsetAsync(flags, 0, (size_t)L_ * NBLK * FLAGSTRIDE * 4, stream);
  convbf_k<<<V_ * H_ / 8 / 256, 256, 0, stream>>>(out_w, ow_bf);
  pack_whh_k<<<L_ * 2048 * 64 / 256, 256, 0, stream>>>(w_hh, whh_pk);
  embed_k<<<BT_ * H_ / 256, 256, 0, stream>>>(indices, emb, x);

  for (int l = 0; l < L_; ++l) {
    gemm_a32_k<true><<<dim3(4 * H_ / 128, BT_ / 128), 256, 0, stream>>>(
        x, w_ih + (size_t)l * 4 * H_ * H_, b_ih + l * 4 * H_, b_hh + l * 4 * H_,
        xg, nullptr, BT_, 4 * H_, H_);
    hipMemsetAsync(hb, 0, (size_t)2 * B_ * H_ * 2, stream);   // zero buf0 hi+lo
    lstm_seq_k<<<NBLK, 512, 0, stream>>>(
        xg, whh_pk + (size_t)l * 4 * H_ * H_, hb, dec,
        flags + (size_t)l * NBLK * FLAGSTRIDE);
    attn_k<<<BT_, 256, 0, stream>>>(dec, enc, de_lens, cat);
    gemm_a32_k<false><<<dim3(H_ / 128, BT_ / 128), 256, 0, stream>>>(
        cat, lin_w + (size_t)l * H_ * 2 * H_, lin_b + l * H_, nullptr,
        x, (l == L_ - 1) ? x_bf : nullptr, BT_, H_, 2 * H_);
  }

  gemm_bb_k<<<30 * (V_ / 128), 256, 0, stream>>>(x_bf, ow_bf, out_b, outp);
}

// Round 5
// 1677.508 us; speedup vs baseline: 1.8180x; 1.8180x over previous
//
#include <hip/hip_runtime.h>
#include <hip/hip_bf16.h>
#include <math.h>

#define B_ 64
#define T_ 60
#define S_ 60
#define H_ 512
#define V_ 32000
#define L_ 2
#define BT_ (B_*T_)
#define LDSROW 40
#define NBLK 32
#define FLAGSTRIDE 32   // ints between flags (128B, separate cache lines)

typedef __attribute__((ext_vector_type(8))) short short8;
typedef __attribute__((ext_vector_type(4))) float f32x4;
typedef __attribute__((ext_vector_type(2))) unsigned long long ull2;

__device__ __forceinline__ short f2bf(float x) {
  __hip_bfloat16 h = __float2bfloat16(x);
  return __builtin_bit_cast(short, h);
}
__device__ __forceinline__ float bf2f(short s) {
  unsigned int u = ((unsigned int)(unsigned short)s) << 16;
  return __builtin_bit_cast(float, u);
}
__device__ __forceinline__ float sigm(float x) { return 1.f / (1.f + __expf(-x)); }
__device__ __forceinline__ float tanh_(float x) {
  float e = __expf(-2.f * fabsf(x));
  float t = (1.f - e) / (1.f + e);
  return x >= 0.f ? t : -t;
}

// ---------------- f32 -> bf16 bulk convert ----------------
__global__ __launch_bounds__(256) void convbf_k(const float* __restrict__ src,
                                                short* __restrict__ dst) {
  int g = blockIdx.x * 256 + threadIdx.x;
  const float* s = src + (size_t)g * 8;
  float4 v0 = *(const float4*)s, v1 = *(const float4*)(s + 4);
  short8 o;
  o[0]=f2bf(v0.x); o[1]=f2bf(v0.y); o[2]=f2bf(v0.z); o[3]=f2bf(v0.w);
  o[4]=f2bf(v1.x); o[5]=f2bf(v1.y); o[6]=f2bf(v1.z); o[7]=f2bf(v1.w);
  *(short8*)(dst + (size_t)g * 8) = o;
}

// ---- pack whh[2,2048,512] f32 -> block-permuted fragment-ordered bf16 ----
// original n = g*512 + j; permuted row np = (j>>4)*64 + g*16 + (j&15)
// frag offset(np,k) = ((np>>4)*64 + (k>>3))*128 + (np&15)*8 + (k&7)
__global__ __launch_bounds__(256) void pack_whh_k(const float* __restrict__ whh,
                                                  short* __restrict__ pk) {
  int idx = blockIdx.x * 256 + threadIdx.x;
  int l = idx >> 17, rem = idx & 131071;
  int n = rem >> 6, k8 = rem & 63;
  int g = n >> 9, j = n & 511;
  int np = (j >> 4) * 64 + g * 16 + (j & 15);
  const float* src = whh + ((size_t)l * 2048 + n) * 512 + k8 * 8;
  float4 v0 = *(const float4*)src, v1 = *(const float4*)(src + 4);
  short8 o;
  o[0]=f2bf(v0.x); o[1]=f2bf(v0.y); o[2]=f2bf(v0.z); o[3]=f2bf(v0.w);
  o[4]=f2bf(v1.x); o[5]=f2bf(v1.y); o[6]=f2bf(v1.z); o[7]=f2bf(v1.w);
  size_t dst = (size_t)l * (2048 * 512) + ((size_t)((np >> 4) * 64 + k8)) * 128 + (np & 15) * 8;
  *(short8*)(pk + dst) = o;
}

// ---------------- embedding gather ----------------
__global__ __launch_bounds__(256) void embed_k(const int* __restrict__ idx,
                                               const float* __restrict__ emb,
                                               float* __restrict__ x) {
  int e = blockIdx.x * 256 + threadIdx.x;
  int bt = e >> 9, h = e & (H_ - 1);
  int row = idx[bt];
  x[e] = emb[(size_t)row * H_ + h];
}

// ------- C = A(f32, split hi/lo) @ Bw(f32->bf16)^T + bias1[+bias2] ----------
template<bool XPOSE>
__global__ __launch_bounds__(256) void gemm_a32_k(
    const float* __restrict__ A, const float* __restrict__ Bw,
    const float* __restrict__ bias1, const float* __restrict__ bias2,
    float* __restrict__ C, short* __restrict__ Cbf, int M, int N, int K) {
  __shared__ short Ahs[128 * LDSROW];
  __shared__ short Als[128 * LDSROW];
  __shared__ short Bs[128 * LDSROW];
  int tid = threadIdx.x;
  int bm = blockIdx.y * 128, bn = blockIdx.x * 128;
  int wid = tid >> 6, lane = tid & 63;
  int wr = wid >> 1, wc = wid & 1;
  int lrow = lane & 15, lk = (lane >> 4) * 8;
  f32x4 acc[4][4];
#pragma unroll
  for (int i = 0; i < 4; ++i)
#pragma unroll
    for (int j = 0; j < 4; ++j) acc[i][j] = (f32x4){0.f, 0.f, 0.f, 0.f};

  int srow = tid >> 2, scol = (tid & 3) * 8;

  for (int k0 = 0; k0 < K; k0 += 32) {
#pragma unroll
    for (int it = 0; it < 2; ++it) {
      int r = srow + it * 64;
      const float* ap = A + (size_t)(bm + r) * K + k0 + scol;
      float4 a0 = *(const float4*)ap, a1 = *(const float4*)(ap + 4);
      float av[8] = {a0.x,a0.y,a0.z,a0.w,a1.x,a1.y,a1.z,a1.w};
      short8 hv, lv;
#pragma unroll
      for (int e = 0; e < 8; ++e) {
        short h = f2bf(av[e]);
        hv[e] = h;
        lv[e] = f2bf(av[e] - bf2f(h));
      }
      *(short8*)(Ahs + r * LDSROW + scol) = hv;
      *(short8*)(Als + r * LDSROW + scol) = lv;
      const float* bp = Bw + (size_t)(bn + r) * K + k0 + scol;
      float4 b0 = *(const float4*)bp, b1 = *(const float4*)(bp + 4);
      short8 bv;
      bv[0]=f2bf(b0.x); bv[1]=f2bf(b0.y); bv[2]=f2bf(b0.z); bv[3]=f2bf(b0.w);
      bv[4]=f2bf(b1.x); bv[5]=f2bf(b1.y); bv[6]=f2bf(b1.z); bv[7]=f2bf(b1.w);
      *(short8*)(Bs + r * LDSROW + scol) = bv;
    }
    __syncthreads();
    short8 ah[4], al[4], bfr[4];
#pragma unroll
    for (int i = 0; i < 4; ++i) {
      ah[i] = *(const short8*)(Ahs + (wr * 64 + i * 16 + lrow) * LDSROW + lk);
      al[i] = *(const short8*)(Als + (wr * 64 + i * 16 + lrow) * LDSROW + lk);
    }
#pragma unroll
    for (int j = 0; j < 4; ++j)
      bfr[j] = *(const short8*)(Bs + (wc * 64 + j * 16 + lrow) * LDSROW + lk);
#pragma unroll
    for (int i = 0; i < 4; ++i)
#pragma unroll
      for (int j = 0; j < 4; ++j) {
        acc[i][j] = __builtin_amdgcn_mfma_f32_16x16x32_bf16(ah[i], bfr[j], acc[i][j], 0, 0, 0);
        acc[i][j] = __builtin_amdgcn_mfma_f32_16x16x32_bf16(al[i], bfr[j], acc[i][j], 0, 0, 0);
      }
    __syncthreads();
  }

#pragma unroll
  for (int j = 0; j < 4; ++j) {
    int col = bn + wc * 64 + j * 16 + lrow;
    float bv = bias1[col] + (bias2 ? bias2[col] : 0.f);
#pragma unroll
    for (int i = 0; i < 4; ++i) {
#pragma unroll
      for (int r = 0; r < 4; ++r) {
        int row = bm + wr * 64 + i * 16 + (lane >> 4) * 4 + r;
        float v = acc[i][j][r] + bv;
        if (XPOSE) {
          int b = row / T_, t = row - b * T_;
          C[((size_t)t * B_ + b) * N + col] = v;
        } else {
          C[(size_t)row * N + col] = v;
          if (Cbf) Cbf[(size_t)row * N + col] = f2bf(v);
        }
      }
    }
  }
}

// ---------------- final: C = A(bf16) @ Bbf(bf16)^T + bias ---------------
__global__ __launch_bounds__(256) void gemm_bb_k(
    const short* __restrict__ A, const short* __restrict__ Bbf,
    const float* __restrict__ bias, float* __restrict__ C) {
  const int N = V_, K = H_;
  int n = blockIdx.x;
  int xcd = n & 7, pos = n >> 3;
  int base = (xcd < 4) ? xcd * 938 : 4 * 938 + (xcd - 4) * 937;
  int wg = base + pos;
  int bm = (wg % 30) * 128;
  int bn = (wg / 30) * 128;

  __shared__ short As[128 * LDSROW];
  __shared__ short Bs[128 * LDSROW];
  int tid = threadIdx.x;
  int wid = tid >> 6, lane = tid & 63;
  int wr = wid >> 1, wc = wid & 1;
  int lrow = lane & 15, lk = (lane >> 4) * 8;
  f32x4 acc[4][4];
#pragma unroll
  for (int i = 0; i < 4; ++i)
#pragma unroll
    for (int j = 0; j < 4; ++j) acc[i][j] = (f32x4){0.f, 0.f, 0.f, 0.f};

  int srow = tid >> 2, scol = (tid & 3) * 8;

  for (int k0 = 0; k0 < K; k0 += 32) {
#pragma unroll
    for (int it = 0; it < 2; ++it) {
      int r = srow + it * 64;
      short8 av = *(const short8*)(A + (size_t)(bm + r) * K + k0 + scol);
      *(short8*)(As + r * LDSROW + scol) = av;
      short8 bv = *(const short8*)(Bbf + (size_t)(bn + r) * K + k0 + scol);
      *(short8*)(Bs + r * LDSROW + scol) = bv;
    }
    __syncthreads();
    short8 af[4], bfr[4];
#pragma unroll
    for (int i = 0; i < 4; ++i)
      af[i] = *(const short8*)(As + (wr * 64 + i * 16 + lrow) * LDSROW + lk);
#pragma unroll
    for (int j = 0; j < 4; ++j)
      bfr[j] = *(const short8*)(Bs + (wc * 64 + j * 16 + lrow) * LDSROW + lk);
#pragma unroll
    for (int i = 0; i < 4; ++i)
#pragma unroll
      for (int j = 0; j < 4; ++j)
        acc[i][j] = __builtin_amdgcn_mfma_f32_16x16x32_bf16(af[i], bfr[j], acc[i][j], 0, 0, 0);
    __syncthreads();
  }

#pragma unroll
  for (int j = 0; j < 4; ++j) {
    int col = bn + wc * 64 + j * 16 + lrow;
    float bv = bias[col];
#pragma unroll
    for (int i = 0; i < 4; ++i)
#pragma unroll
      for (int r = 0; r < 4; ++r) {
        int row = bm + wr * 64 + i * 16 + (lane >> 4) * 4 + r;
        C[(size_t)row * N + col] = acc[i][j][r] + bv;
      }
  }
}

// ------------- persistent LSTM, 32 blocks, fence-free LLC exchange ----------
// Block jb owns j in [jb*16, jb*16+16), all 4 gates. Wave w: mtile=w>>1
// (16 batches), kh=w&1 (K half). whh fragment resident in VGPRs.
// h: hi/lo bf16 planes, double buffered, accessed ONLY via relaxed
// agent-scope atomics (sc1: write-through, L2-bypass -> coherent via LLC).
// No fences -> no buffer_wbl2/inv -> L2 stays warm for xg.
__global__ __launch_bounds__(512, 2) void lstm_seq_k(
    const float* __restrict__ xg,      // [T,B,4H], both biases pre-added
    const short* __restrict__ whh_pk,  // packed bf16
    short* __restrict__ hb,            // 2 bufs x (hi 32768 | lo 32768) shorts
    float* __restrict__ dec,           // [B,T,H]
    int* __restrict__ flags) {
  __shared__ float gall[2][64 * 65];
  int tid = threadIdx.x;
  int jb = blockIdx.x;
  int w = tid >> 6, lane = tid & 63;
  int lr = lane & 15, lkg = lane >> 4;
  int mtile = w >> 1, kh = w & 1;

  short8 wreg[4][8];
#pragma unroll
  for (int nt = 0; nt < 4; ++nt)
#pragma unroll
    for (int k8 = 0; k8 < 8; ++k8) {
      int rowtile = jb * 4 + nt;
      int kt = kh * 8 + k8;
      wreg[nt][k8] = *(const short8*)(whh_pk +
          ((size_t)(rowtile * 64 + kt * 4 + lkg)) * 128 + lr * 8);
    }

  // epilogue mapping: 2 adjacent j per thread (4B h stores)
  const int jp = tid & 7;
  const int half = (tid >> 3) & 1;
  const int be = (tid >> 4) + half * 32;   // batch 0..63
  const int j0 = jp * 2;
  const int jglob0 = jb * 16 + j0;
  float cc[2] = {0.f, 0.f};

  const int aoff = (mtile * 16 + lr) * 512 + kh * 256 + lkg * 8;

  for (int t = 0; t < T_; ++t) {
    // xg prefetch (independent of h; hides under the poll)
    float2 xgv[4];
    const float* xb = xg + ((size_t)t * B_ + be) * 2048 + jglob0;
#pragma unroll
    for (int g = 0; g < 4; ++g) xgv[g] = *(const float2*)(xb + g * 512);

    // wait for the 16 producers of our K half
    if (t > 0) {
      if (lane < 16) {
        const int* fp = flags + (kh * 16 + lane) * FLAGSTRIDE;
        while (__hip_atomic_load(fp, __ATOMIC_RELAXED, __HIP_MEMORY_SCOPE_AGENT) < t) {}
      }
      asm volatile("" ::: "memory");   // compiler barrier only; no cache ops
    }

    const short* rh = hb + (size_t)(t & 1) * 65536;
    const short* rl = rh + 32768;
    f32x4 acc[4];
#pragma unroll
    for (int nt = 0; nt < 4; ++nt) acc[nt] = (f32x4){0.f, 0.f, 0.f, 0.f};
#pragma unroll
    for (int k8 = 0; k8 < 8; ++k8) {
      const unsigned long long* ph = (const unsigned long long*)(rh + aoff + k8 * 32);
      const unsigned long long* pl = (const unsigned long long*)(rl + aoff + k8 * 32);
      ull2 vh, vl;
      vh[0] = __hip_atomic_load(ph,     __ATOMIC_RELAXED, __HIP_MEMORY_SCOPE_AGENT);
      vh[1] = __hip_atomic_load(ph + 1, __ATOMIC_RELAXED, __HIP_MEMORY_SCOPE_AGENT);
      vl[0] = __hip_atomic_load(pl,     __ATOMIC_RELAXED, __HIP_MEMORY_SCOPE_AGENT);
      vl[1] = __hip_atomic_load(pl + 1, __ATOMIC_RELAXED, __HIP_MEMORY_SCOPE_AGENT);
      short8 ah = __builtin_bit_cast(short8, vh);
      short8 al = __builtin_bit_cast(short8, vl);
#pragma unroll
      for (int nt = 0; nt < 4; ++nt) {
        acc[nt] = __builtin_amdgcn_mfma_f32_16x16x32_bf16(ah, wreg[nt][k8], acc[nt], 0, 0, 0);
        acc[nt] = __builtin_amdgcn_mfma_f32_16x16x32_bf16(al, wreg[nt][k8], acc[nt], 0, 0, 0);
      }
    }
#pragma unroll
    for (int nt = 0; nt < 4; ++nt)
#pragma unroll
      for (int r = 0; r < 4; ++r)
        gall[kh][(nt * 16 + lr) * 65 + mtile * 16 + lkg * 4 + r] = acc[nt][r];
    __syncthreads();

    short* wh = hb + (size_t)((t & 1) ^ 1) * 65536;
    float hn2[2];
#pragma unroll
    for (int jj = 0; jj < 2; ++jj) {
      int j = j0 + jj;
      float gv[4];
#pragma unroll
      for (int g = 0; g < 4; ++g)
        gv[g] = gall[0][(g * 16 + j) * 65 + be] + gall[1][(g * 16 + j) * 65 + be]
              + (jj ? xgv[g].y : xgv[g].x);
      float cn = sigm(gv[1]) * cc[jj] + sigm(gv[0]) * tanh_(gv[2]);
      hn2[jj] = sigm(gv[3]) * tanh_(cn);
      cc[jj] = cn;
    }
    short hi0 = f2bf(hn2[0]), hi1 = f2bf(hn2[1]);
    short lo0 = f2bf(hn2[0] - bf2f(hi0)), lo1 = f2bf(hn2[1] - bf2f(hi1));
    unsigned int hpack = (unsigned int)(unsigned short)hi0 |
                         ((unsigned int)(unsigned short)hi1 << 16);
    unsigned int lpack = (unsigned int)(unsigned short)lo0 |
                         ((unsigned int)(unsigned short)lo1 << 16);
    unsigned int* whw = (unsigned int*)wh + (size_t)be * 256 + (jglob0 >> 1);
    __hip_atomic_store(whw,         hpack, __ATOMIC_RELAXED, __HIP_MEMORY_SCOPE_AGENT);
    __hip_atomic_store(whw + 16384, lpack, __ATOMIC_RELAXED, __HIP_MEMORY_SCOPE_AGENT);
    float2 dv; dv.x = hn2[0]; dv.y = hn2[1];
    *(float2*)(dec + ((size_t)be * T_ + t) * H_ + jglob0) = dv;

    __syncthreads();   // drains every wave's stores (vmcnt) before flag
    if (tid == 0)
      __hip_atomic_store(flags + jb * FLAGSTRIDE, t + 1,
                         __ATOMIC_RELAXED, __HIP_MEMORY_SCOPE_AGENT);
  }
}

// ---------------- attention + softmax + concat (f32) ----------------
__global__ __launch_bounds__(256) void attn_k(const float* __restrict__ dec,
                                              const float* __restrict__ enc,
                                              const int* __restrict__ lens,
                                              float* __restrict__ cat) {
  int bt = blockIdx.x;
  int b = bt / T_;
  __shared__ float dsh[H_];
  __shared__ float p[64];
  int tid = threadIdx.x;
  dsh[tid] = dec[(size_t)bt * H_ + tid];
  dsh[tid + 256] = dec[(size_t)bt * H_ + tid + 256];
  __syncthreads();
  int wid = tid >> 6, lane = tid & 63;
  int len = lens[b];
  for (int s = wid; s < S_; s += 4) {
    const float* er = enc + ((size_t)(b * S_ + s)) * H_ + lane * 8;
    float4 e0 = *(const float4*)er, e1 = *(const float4*)(er + 4);
    const float* dr = dsh + lane * 8;
    float sum = e0.x*dr[0] + e0.y*dr[1] + e0.z*dr[2] + e0.w*dr[3]
              + e1.x*dr[4] + e1.y*dr[5] + e1.z*dr[6] + e1.w*dr[7];
#pragma unroll
    for (int off = 32; off > 0; off >>= 1) sum += __shfl_down(sum, off);
    if (lane == 0) p[s] = sum + (s < len ? 0.f : -1.0e9f);
  }
  __syncthreads();
  if (wid == 0) {
    float v = (lane < S_) ? p[lane] : -INFINITY;
    float m = v;
#pragma unroll
    for (int off = 32; off > 0; off >>= 1) m = fmaxf(m, __shfl_down(m, off));
    m = __shfl(m, 0);
    float e = (lane < S_) ? expf(v - m) : 0.f;
    float ssum = e;
#pragma unroll
    for (int off = 32; off > 0; off >>= 1) ssum += __shfl_down(ssum, off);
    ssum = __shfl(ssum, 0);
    if (lane < S_) p[lane] = e / ssum;
  }
  __syncthreads();
  int h = tid * 2;
  float a0 = 0.f, a1 = 0.f;
  for (int s = 0; s < S_; ++s) {
    float ps = p[s];
    const float* er = enc + ((size_t)(b * S_ + s)) * H_ + h;
    a0 += ps * er[0];
    a1 += ps * er[1];
  }
  size_t base = (size_t)bt * (2 * H_);
  cat[base + h]          = dsh[h];
  cat[base + h + 1]      = dsh[h + 1];
  cat[base + H_ + h]     = a0;
  cat[base + H_ + h + 1] = a1;
}

extern "C" void kernel_launch(void* const* d_in, const int* in_sizes, int n_in,
                              void* d_out, int out_size, void* d_ws, size_t ws_size,
                              hipStream_t stream) {
  (void)in_sizes; (void)n_in; (void)out_size; (void)ws_size;
  const int*   indices = (const int*)d_in[0];
  const float* enc     = (const float*)d_in[1];
  const int*   de_lens = (const int*)d_in[2];
  const float* emb     = (const float*)d_in[3];
  const float* w_ih    = (const float*)d_in[4];
  const float* w_hh    = (const float*)d_in[5];
  const float* b_ih    = (const float*)d_in[6];
  const float* b_hh    = (const float*)d_in[7];
  const float* lin_w   = (const float*)d_in[8];
  const float* lin_b   = (const float*)d_in[9];
  const float* out_w   = (const float*)d_in[10];
  const float* out_b   = (const float*)d_in[11];
  float* outp = (float*)d_out;

  char* ws = (char*)d_ws;
  size_t off = 0;
  auto alloc = [&](size_t bytes) -> void* {
    void* p = ws + off; off += (bytes + 255) & ~(size_t)255; return p;
  };
  float* x      = (float*)alloc((size_t)BT_ * H_ * 4);
  float* xg     = (float*)alloc((size_t)BT_ * 4 * H_ * 4);      // [T,B,4H]
  float* dec    = (float*)alloc((size_t)BT_ * H_ * 4);          // [B,T,H]
  float* cat    = (float*)alloc((size_t)BT_ * 2 * H_ * 4);
  short* ow_bf  = (short*)alloc((size_t)V_ * H_ * 2);
  short* whh_pk = (short*)alloc((size_t)L_ * 4 * H_ * H_ * 2);
  short* x_bf   = (short*)alloc((size_t)BT_ * H_ * 2);
  short* hb     = (short*)alloc((size_t)4 * B_ * H_ * 2);       // 2 bufs x hi/lo
  int*   flags  = (int*)alloc((size_t)L_ * NBLK * FLAGSTRIDE * 4);

  hipMemsetAsync(flags, 0, (size_t)L_ * NBLK * FLAGSTRIDE * 4, stream);
  convbf_k<<<V_ * H_ / 8 / 256, 256, 0, stream>>>(out_w, ow_bf);
  pack_whh_k<<<L_ * 2048 * 64 / 256, 256, 0, stream>>>(w_hh, whh_pk);
  embed_k<<<BT_ * H_ / 256, 256, 0, stream>>>(indices, emb, x);

  for (int l = 0; l < L_; ++l) {
    gemm_a32_k<true><<<dim3(4 * H_ / 128, BT_ / 128), 256, 0, stream>>>(
        x, w_ih + (size_t)l * 4 * H_ * H_, b_ih + l * 4 * H_, b_hh + l * 4 * H_,
        xg, nullptr, BT_, 4 * H_, H_);
    hipMemsetAsync(hb, 0, (size_t)2 * B_ * H_ * 2, stream);   // zero buf0 hi+lo
    lstm_seq_k<<<NBLK, 512, 0, stream>>>(
        xg, whh_pk + (size_t)l * 4 * H_ * H_, hb, dec,
        flags + (size_t)l * NBLK * FLAGSTRIDE);
    attn_k<<<BT_, 256, 0, stream>>>(dec, enc, de_lens, cat);
    gemm_a32_k<false><<<dim3(H_ / 128, BT_ / 128), 256, 0, stream>>>(
        cat, lin_w + (size_t)l * H_ * 2 * H_, lin_b + l * H_, nullptr,
        x, (l == L_ - 1) ? x_bf : nullptr, BT_, H_, 2 * H_);
  }

  gemm_bb_k<<<30 * (V_ / 128), 256, 0, stream>>>(x_bf, ow_bf, out_b, outp);
}